// Round 2
// baseline (523.504 us; speedup 1.0000x reference)
//
#include <hip/hip_runtime.h>
#include <hip/hip_bf16.h>

#define N_NODES 50000
#define N_EDGES 400000
#define FIN     128
#define HD      512
#define SLOPE   0.2f
#define SRC_CAP 512

typedef __hip_bfloat16 bf16;
typedef __bf16 bf16x8 __attribute__((ext_vector_type(8)));
typedef __bf16 bf16x4 __attribute__((ext_vector_type(4)));
typedef float  f32x4  __attribute__((ext_vector_type(4)));

__device__ __forceinline__ float tof(bf16 x) { return __bfloat162float(x); }

// ---------------- sentinel (workspace too small diagnostic) ----------------
__global__ void sentinel_k(float* out, int n) {
    int i = blockIdx.x * 256 + threadIdx.x;
    if (i < n) out[i] = 12288.0f;
}

// ---------------- X f32 -> bf16 ----------------
__global__ __launch_bounds__(256) void conv_k(const float* __restrict__ X, bf16* __restrict__ Xb) {
    int i = blockIdx.x * 256 + threadIdx.x;   // one float4 per thread
    const int total = N_NODES * FIN / 4;
    if (i < total) {
        float4 v = reinterpret_cast<const float4*>(X)[i];
        bf16x4 o = {(__bf16)v.x, (__bf16)v.y, (__bf16)v.z, (__bf16)v.w};
        *reinterpret_cast<bf16x4*>(reinterpret_cast<__bf16*>(Xb) + (size_t)i * 4) = o;
    }
}

// ---------------- prep: transpose W1/Wres1 (f32) -> bf16 [512][128] ----------------
__global__ void transpose_k(const float* __restrict__ W1, const float* __restrict__ Wres1,
                            bf16* __restrict__ W1T, bf16* __restrict__ WresT) {
    int c = blockIdx.x;      // 0..511
    int k = threadIdx.x;     // 0..127
    if (blockIdx.y == 0) W1T[c * FIN + k]   = __float2bfloat16(W1[k * HD + c]);
    else                 WresT[c * FIN + k] = __float2bfloat16(Wres1[k * HD + c]);
}

// ---------------- prep: wl[k][h] = sum_d W1[k, h*128+d] * al1[h,d] ----------------
__global__ void wlr_k(const float* __restrict__ W1, const float* __restrict__ al1,
                      const float* __restrict__ ar1, float* __restrict__ wl, float* __restrict__ wr) {
    int i = blockIdx.x * 256 + threadIdx.x;   // 0..511
    int k = i >> 2, h = i & 3;
    float sl = 0.f, sr = 0.f;
    for (int d = 0; d < 128; ++d) {
        float w = W1[k * HD + h * 128 + d];
        sl += w * al1[h * 128 + d];
        sr += w * ar1[h * 128 + d];
    }
    wl[k * 4 + h] = sl;
    wr[k * 4 + h] = sr;
}

// ---------------- el/er per node: wave-per-node ----------------
__global__ __launch_bounds__(256) void eler_k(const float* __restrict__ X,
                                              const float* __restrict__ wl, const float* __restrict__ wr,
                                              float* __restrict__ el, float* __restrict__ er) {
    int w = threadIdx.x >> 6, lane = threadIdx.x & 63;
    int n = blockIdx.x * 4 + w;
    float x1 = X[(size_t)n * FIN + lane];
    float x2 = X[(size_t)n * FIN + 64 + lane];
    float pl[4], pr[4];
#pragma unroll
    for (int h = 0; h < 4; ++h) {
        pl[h] = x1 * wl[lane * 4 + h] + x2 * wl[(lane + 64) * 4 + h];
        pr[h] = x1 * wr[lane * 4 + h] + x2 * wr[(lane + 64) * 4 + h];
    }
#pragma unroll
    for (int off = 32; off > 0; off >>= 1) {
#pragma unroll
        for (int h = 0; h < 4; ++h) {
            pl[h] += __shfl_xor(pl[h], off);
            pr[h] += __shfl_xor(pr[h], off);
        }
    }
    if (lane == 0) {
        *reinterpret_cast<float4*>(el + (size_t)n * 4) = make_float4(pl[0], pl[1], pl[2], pl[3]);
        *reinterpret_cast<float4*>(er + (size_t)n * 4) = make_float4(pr[0], pr[1], pr[2], pr[3]);
    }
}

// ---------------- CSR build ----------------
__global__ void hist_k(const int* __restrict__ dst, int* __restrict__ deg) {
    int e = blockIdx.x * 256 + threadIdx.x;
    if (e < N_EDGES) atomicAdd(&deg[dst[e]], 1);
}

__global__ __launch_bounds__(1024) void scan_k(const int* __restrict__ deg,
                                               int* __restrict__ rowptr, int* __restrict__ cursor) {
    __shared__ int s[1024];
    const int ITEMS = (N_NODES + 1023) / 1024;   // 49
    int t = threadIdx.x;
    int base = t * ITEMS;
    int sum = 0;
    for (int i = 0; i < ITEMS; ++i) {
        int idx = base + i;
        if (idx < N_NODES) sum += deg[idx];
    }
    s[t] = sum;
    __syncthreads();
    for (int off = 1; off < 1024; off <<= 1) {
        int v = (t >= off) ? s[t - off] : 0;
        __syncthreads();
        s[t] += v;
        __syncthreads();
    }
    int run = s[t] - sum;   // exclusive prefix
    for (int i = 0; i < ITEMS; ++i) {
        int idx = base + i;
        if (idx < N_NODES) {
            rowptr[idx] = run;
            cursor[idx] = run;
            run += deg[idx];
        }
    }
    if (t == 1023) rowptr[N_NODES] = s[1023];
}

__global__ void fill_k(const int* __restrict__ src, const int* __restrict__ dst,
                       int* __restrict__ cursor, int* __restrict__ csr) {
    int e = blockIdx.x * 256 + threadIdx.x;
    if (e < N_EDGES) {
        int pos = atomicAdd(&cursor[dst[e]], 1);
        csr[pos] = src[e];
    }
}

// ---------------- MFMA GEMM: Z = X@W1 (y=0), RES = X@Wres1 + b1 (y=1) ----------------
__global__ __launch_bounds__(256) void gemm_k(const bf16* __restrict__ X,
                                              const bf16* __restrict__ W1T, const bf16* __restrict__ WresT,
                                              const float* __restrict__ bias1,
                                              bf16* __restrict__ Z, bf16* __restrict__ RES) {
    const bf16* BT = blockIdx.y ? WresT : W1T;
    bf16* outp = blockIdx.y ? RES : Z;
    const bool useBias = (blockIdx.y != 0);
    const int w = threadIdx.x >> 6;
    const int lane = threadIdx.x & 63;
    const int cl = lane & 15;        // A row within tile / D col / store row
    const int rg = lane >> 4;        // 0..3
    const int khi = rg * 8;
    const int cg = rg * 4;
    const int m0 = blockIdx.x * 64 + w * 16;
    const int row = m0 + cl;
    const int rowc = row < N_NODES ? row : N_NODES - 1;

    const bf16x8* xr = reinterpret_cast<const bf16x8*>(X + (size_t)rowc * FIN + khi);
    bf16x8 a0 = xr[0], a1 = xr[4], a2 = xr[8], a3 = xr[12];   // k = khi + 32*ks

    __shared__ float sbuf[4][16][17];

    for (int t = 0; t < 32; ++t) {
        const int c0 = t * 16;
        const bf16x8* bp = reinterpret_cast<const bf16x8*>(BT + (size_t)(c0 + cl) * FIN + khi);
        bf16x8 b0 = bp[0], b1 = bp[4], b2 = bp[8], b3 = bp[12];
        float bv = useBias ? bias1[c0 + cl] : 0.0f;
        f32x4 acc = {bv, bv, bv, bv};
        acc = __builtin_amdgcn_mfma_f32_16x16x32_bf16(a0, b0, acc, 0, 0, 0);
        acc = __builtin_amdgcn_mfma_f32_16x16x32_bf16(a1, b1, acc, 0, 0, 0);
        acc = __builtin_amdgcn_mfma_f32_16x16x32_bf16(a2, b2, acc, 0, 0, 0);
        acc = __builtin_amdgcn_mfma_f32_16x16x32_bf16(a3, b3, acc, 0, 0, 0);
        // D frag: col = lane&15, row = (lane>>4)*4 + i  -> transpose via per-wave LDS
#pragma unroll
        for (int i = 0; i < 4; ++i) sbuf[w][rg * 4 + i][cl] = acc[i];
        asm volatile("s_waitcnt lgkmcnt(0)" ::: "memory");
        if (row < N_NODES) {
            bf16x4 sv = {(__bf16)sbuf[w][cl][cg + 0], (__bf16)sbuf[w][cl][cg + 1],
                         (__bf16)sbuf[w][cl][cg + 2], (__bf16)sbuf[w][cl][cg + 3]};
            *reinterpret_cast<bf16x4*>(outp + (size_t)row * HD + c0 + cg) = sv;
        }
        asm volatile("s_waitcnt lgkmcnt(0)" ::: "memory");
    }
}

// ---------------- layer-1 aggregation + BN + ELU + layer-2 projections ----------------
__global__ __launch_bounds__(256) void agg1_k(
    const int* __restrict__ rowptr, const int* __restrict__ csr,
    const float* __restrict__ el, const float* __restrict__ er,
    const bf16* __restrict__ Z, const bf16* __restrict__ RES,
    const float* __restrict__ bng, const float* __restrict__ bnb,
    const float* __restrict__ bnm, const float* __restrict__ bnv,
    const float* __restrict__ W2, const float* __restrict__ Wres2,
    const float* __restrict__ al2, const float* __restrict__ ar2,
    float* __restrict__ z2, float* __restrict__ res2,
    float* __restrict__ el2, float* __restrict__ er2) {
    __shared__ int ssrc[SRC_CAP];
    __shared__ float4 red4[256];
    __shared__ float wsum[4][6];

    const int n = blockIdx.x;
    const int t = threadIdx.x;
    const int beg = rowptr[n];
    const int deg = rowptr[n + 1] - beg;
    const float4 ern = *reinterpret_cast<const float4*>(er + (size_t)n * 4);

    // pass 1: per-head max (and stage src ids in LDS)
    float m0 = -1e30f, m1 = -1e30f, m2 = -1e30f, m3 = -1e30f;
    for (int j = t; j < deg; j += 256) {
        int s = csr[beg + j];
        if (j < SRC_CAP) ssrc[j] = s;
        float4 e4 = *reinterpret_cast<const float4*>(el + (size_t)s * 4);
        float e;
        e = e4.x + ern.x; e = e > 0.f ? e : SLOPE * e; m0 = fmaxf(m0, e);
        e = e4.y + ern.y; e = e > 0.f ? e : SLOPE * e; m1 = fmaxf(m1, e);
        e = e4.z + ern.z; e = e > 0.f ? e : SLOPE * e; m2 = fmaxf(m2, e);
        e = e4.w + ern.w; e = e > 0.f ? e : SLOPE * e; m3 = fmaxf(m3, e);
    }
    red4[t] = make_float4(m0, m1, m2, m3);
    __syncthreads();
#pragma unroll
    for (int sft = 128; sft > 0; sft >>= 1) {
        if (t < sft) {
            float4 o = red4[t + sft];
            float4 a = red4[t];
            a.x = fmaxf(a.x, o.x); a.y = fmaxf(a.y, o.y);
            a.z = fmaxf(a.z, o.z); a.w = fmaxf(a.w, o.w);
            red4[t] = a;
        }
        __syncthreads();
    }
    const float4 M4 = red4[0];

    // pass 2: softmax-weighted gather. thread owns dims d1=t (head h1), d2=t+256 (head h1+2)
    const int h1 = t >> 7;
    const float Mh1 = h1 ? M4.y : M4.x;
    const float Mh2 = h1 ? M4.w : M4.z;
    const float eh1 = h1 ? ern.y : ern.x;
    const float eh2 = h1 ? ern.w : ern.z;
    const int d1 = t, d2 = t + 256;
    float acc1 = 0.f, acc2 = 0.f, den1 = 0.f, den2 = 0.f;
    for (int j = 0; j < deg; ++j) {
        int s = (j < SRC_CAP) ? ssrc[j] : csr[beg + j];
        const float* ep = el + (size_t)s * 4;
        float e1 = ep[h1] + eh1;     e1 = e1 > 0.f ? e1 : SLOPE * e1;
        float e2 = ep[h1 + 2] + eh2; e2 = e2 > 0.f ? e2 : SLOPE * e2;
        float p1 = __expf(e1 - Mh1);
        float p2 = __expf(e2 - Mh2);
        den1 += p1; den2 += p2;
        const bf16* zr = Z + (size_t)s * HD;
        acc1 += p1 * tof(zr[d1]);
        acc2 += p2 * tof(zr[d2]);
    }
    float inv1 = (deg > 0) ? 1.f / den1 : 0.f;
    float inv2 = (deg > 0) ? 1.f / den2 : 0.f;

    // + residual(+b1 folded), BN, ELU
    float o1 = acc1 * inv1 + tof(RES[(size_t)n * HD + d1]);
    float o2 = acc2 * inv2 + tof(RES[(size_t)n * HD + d2]);
    o1 = (o1 - bnm[d1]) * rsqrtf(bnv[d1] + 1e-5f) * bng[d1] + bnb[d1];
    o2 = (o2 - bnm[d2]) * rsqrtf(bnv[d2] + 1e-5f) * bng[d2] + bnb[d2];
    o1 = o1 > 0.f ? o1 : (__expf(o1) - 1.f);
    o2 = o2 > 0.f ? o2 : (__expf(o2) - 1.f);

    // layer-2 projections: z2 = h@W2, res2 = h@Wres2 (block reduce 6 scalars)
    float pz0 = o1 * W2[d1 * 3 + 0] + o2 * W2[d2 * 3 + 0];
    float pz1 = o1 * W2[d1 * 3 + 1] + o2 * W2[d2 * 3 + 1];
    float pz2 = o1 * W2[d1 * 3 + 2] + o2 * W2[d2 * 3 + 2];
    float pr0 = o1 * Wres2[d1 * 3 + 0] + o2 * Wres2[d2 * 3 + 0];
    float pr1 = o1 * Wres2[d1 * 3 + 1] + o2 * Wres2[d2 * 3 + 1];
    float pr2 = o1 * Wres2[d1 * 3 + 2] + o2 * Wres2[d2 * 3 + 2];
#pragma unroll
    for (int off = 32; off > 0; off >>= 1) {
        pz0 += __shfl_xor(pz0, off); pz1 += __shfl_xor(pz1, off); pz2 += __shfl_xor(pz2, off);
        pr0 += __shfl_xor(pr0, off); pr1 += __shfl_xor(pr1, off); pr2 += __shfl_xor(pr2, off);
    }
    if ((t & 63) == 0) {
        int wv = t >> 6;
        wsum[wv][0] = pz0; wsum[wv][1] = pz1; wsum[wv][2] = pz2;
        wsum[wv][3] = pr0; wsum[wv][4] = pr1; wsum[wv][5] = pr2;
    }
    __syncthreads();
    if (t == 0) {
        float a0 = wsum[0][0] + wsum[1][0] + wsum[2][0] + wsum[3][0];
        float a1 = wsum[0][1] + wsum[1][1] + wsum[2][1] + wsum[3][1];
        float a2 = wsum[0][2] + wsum[1][2] + wsum[2][2] + wsum[3][2];
        float r0 = wsum[0][3] + wsum[1][3] + wsum[2][3] + wsum[3][3];
        float r1 = wsum[0][4] + wsum[1][4] + wsum[2][4] + wsum[3][4];
        float r2 = wsum[0][5] + wsum[1][5] + wsum[2][5] + wsum[3][5];
        z2[(size_t)n * 3 + 0] = a0; z2[(size_t)n * 3 + 1] = a1; z2[(size_t)n * 3 + 2] = a2;
        res2[(size_t)n * 3 + 0] = r0; res2[(size_t)n * 3 + 1] = r1; res2[(size_t)n * 3 + 2] = r2;
        el2[n] = a0 * al2[0] + a1 * al2[1] + a2 * al2[2];
        er2[n] = a0 * ar2[0] + a1 * ar2[1] + a2 * ar2[2];
    }
}

// ---------------- layer-2 aggregation: wave-per-node ----------------
__global__ __launch_bounds__(256) void agg2_k(const int* __restrict__ rowptr, const int* __restrict__ csr,
                                              const float* __restrict__ el2, const float* __restrict__ er2,
                                              const float* __restrict__ z2, const float* __restrict__ res2,
                                              const float* __restrict__ b2, float* __restrict__ out) {
    int wv = threadIdx.x >> 6, lane = threadIdx.x & 63;
    int n = blockIdx.x * 4 + wv;
    int beg = rowptr[n], deg = rowptr[n + 1] - beg;
    float ern = er2[n];
    float m = -1e30f;
    for (int j = lane; j < deg; j += 64) {
        int s = csr[beg + j];
        float e = el2[s] + ern;
        e = e > 0.f ? e : SLOPE * e;
        m = fmaxf(m, e);
    }
#pragma unroll
    for (int off = 32; off > 0; off >>= 1) m = fmaxf(m, __shfl_xor(m, off));
    float den = 0.f, a0 = 0.f, a1 = 0.f, a2 = 0.f;
    for (int j = lane; j < deg; j += 64) {
        int s = csr[beg + j];
        float e = el2[s] + ern;
        e = e > 0.f ? e : SLOPE * e;
        float p = __expf(e - m);
        den += p;
        const float* zp = z2 + (size_t)s * 3;
        a0 += p * zp[0]; a1 += p * zp[1]; a2 += p * zp[2];
    }
#pragma unroll
    for (int off = 32; off > 0; off >>= 1) {
        den += __shfl_xor(den, off);
        a0 += __shfl_xor(a0, off); a1 += __shfl_xor(a1, off); a2 += __shfl_xor(a2, off);
    }
    if (lane == 0) {
        float inv = deg > 0 ? 1.f / den : 0.f;
        out[(size_t)n * 3 + 0] = a0 * inv + res2[(size_t)n * 3 + 0] + b2[0];
        out[(size_t)n * 3 + 1] = a1 * inv + res2[(size_t)n * 3 + 1] + b2[1];
        out[(size_t)n * 3 + 2] = a2 * inv + res2[(size_t)n * 3 + 2] + b2[2];
    }
}

extern "C" void kernel_launch(void* const* d_in, const int* in_sizes, int n_in,
                              void* d_out, int out_size, void* d_ws, size_t ws_size,
                              hipStream_t stream) {
    const float* X     = (const float*)d_in[0];
    const int*   src   = (const int*)d_in[1];
    const int*   dst   = (const int*)d_in[2];
    const float* W1    = (const float*)d_in[3];
    const float* al1   = (const float*)d_in[4];
    const float* ar1   = (const float*)d_in[5];
    const float* b1    = (const float*)d_in[6];
    const float* Wres1 = (const float*)d_in[7];
    const float* bng   = (const float*)d_in[8];
    const float* bnb   = (const float*)d_in[9];
    const float* bnm   = (const float*)d_in[10];
    const float* bnv   = (const float*)d_in[11];
    const float* W2    = (const float*)d_in[12];
    const float* al2   = (const float*)d_in[13];
    const float* ar2   = (const float*)d_in[14];
    const float* b2    = (const float*)d_in[15];
    const float* Wres2 = (const float*)d_in[16];
    float* out = (float*)d_out;

    char* p = (char*)d_ws;
    auto carve = [&](size_t bytes) -> char* {
        char* r = p;
        p += (bytes + 255) & ~(size_t)255;
        return r;
    };
    bf16*  Xb     = (bf16*)carve((size_t)N_NODES * FIN * 2);
    bf16*  W1T    = (bf16*)carve((size_t)HD * FIN * 2);
    bf16*  WresT  = (bf16*)carve((size_t)HD * FIN * 2);
    float* wl     = (float*)carve((size_t)FIN * 4 * 4);
    float* wr     = (float*)carve((size_t)FIN * 4 * 4);
    float* el     = (float*)carve((size_t)N_NODES * 4 * 4);
    float* er     = (float*)carve((size_t)N_NODES * 4 * 4);
    int*   deg    = (int*)carve((size_t)N_NODES * 4);
    int*   rowptr = (int*)carve((size_t)(N_NODES + 1) * 4);
    int*   cursor = (int*)carve((size_t)N_NODES * 4);
    int*   csr    = (int*)carve((size_t)N_EDGES * 4);
    bf16*  Z      = (bf16*)carve((size_t)N_NODES * HD * 2);
    bf16*  RES    = (bf16*)carve((size_t)N_NODES * HD * 2);
    float* z2     = (float*)carve((size_t)N_NODES * 3 * 4);
    float* res2   = (float*)carve((size_t)N_NODES * 3 * 4);
    float* el2    = (float*)carve((size_t)N_NODES * 4);
    float* er2    = (float*)carve((size_t)N_NODES * 4);
    size_t need = (size_t)(p - (char*)d_ws);
    if (need > ws_size) {
        sentinel_k<<<(out_size + 255) / 256, 256, 0, stream>>>(out, out_size);
        return;
    }

    hipMemsetAsync(deg, 0, (size_t)N_NODES * 4, stream);
    conv_k<<<(N_NODES * FIN / 4 + 255) / 256, 256, 0, stream>>>(X, Xb);
    transpose_k<<<dim3(HD, 2), FIN, 0, stream>>>(W1, Wres1, W1T, WresT);
    wlr_k<<<2, 256, 0, stream>>>(W1, al1, ar1, wl, wr);
    eler_k<<<N_NODES / 4, 256, 0, stream>>>(X, wl, wr, el, er);
    hist_k<<<(N_EDGES + 255) / 256, 256, 0, stream>>>(dst, deg);
    scan_k<<<1, 1024, 0, stream>>>(deg, rowptr, cursor);
    fill_k<<<(N_EDGES + 255) / 256, 256, 0, stream>>>(src, dst, cursor, csr);
    gemm_k<<<dim3((N_NODES + 63) / 64, 2), 256, 0, stream>>>(Xb, W1T, WresT, b1, Z, RES);
    agg1_k<<<N_NODES, 256, 0, stream>>>(rowptr, csr, el, er, Z, RES,
                                        bng, bnb, bnm, bnv, W2, Wres2, al2, ar2,
                                        z2, res2, el2, er2);
    agg2_k<<<N_NODES / 4, 256, 0, stream>>>(rowptr, csr, el2, er2, z2, res2, b2, out);
}

// Round 3
// 417.429 us; speedup vs baseline: 1.2541x; 1.2541x over previous
//
#include <hip/hip_runtime.h>
#include <hip/hip_bf16.h>

#define N_NODES 50000
#define N_EDGES 400000
#define FIN     128
#define HD      512
#define SLOPE   0.2f

typedef __hip_bfloat16 bf16;
typedef __bf16 bf16x8 __attribute__((ext_vector_type(8)));
typedef __bf16 bf16x4 __attribute__((ext_vector_type(4)));
typedef float  f32x4  __attribute__((ext_vector_type(4)));

// ---------------- sentinel (workspace too small diagnostic) ----------------
__global__ void sentinel_k(float* out, int n) {
    int i = blockIdx.x * 256 + threadIdx.x;
    if (i < n) out[i] = 12288.0f;
}

// ---------------- prep: zero deg | transpose W1/Wres1 -> bf16 | wl/wr ----------------
__global__ __launch_bounds__(256) void prep_k(const float* __restrict__ W1, const float* __restrict__ Wres1,
                                              const float* __restrict__ al1, const float* __restrict__ ar1,
                                              bf16* __restrict__ W1T, bf16* __restrict__ WresT,
                                              float* __restrict__ wl, float* __restrict__ wr,
                                              int* __restrict__ deg) {
    int b = blockIdx.x;
    if (b < 196) {                       // zero deg
        int i = b * 256 + threadIdx.x;
        if (i < N_NODES) deg[i] = 0;
        return;
    }
    b -= 196;
    if (b < 512) {                       // transpose both weight matrices, 2 col-units/block
        int cu = b * 2 + (threadIdx.x >> 7);
        int k = threadIdx.x & 127;
        if (cu < 512) W1T[cu * FIN + k] = __float2bfloat16(W1[k * HD + cu]);
        else          WresT[(cu - 512) * FIN + k] = __float2bfloat16(Wres1[k * HD + (cu - 512)]);
        return;
    }
    b -= 512;                            // wl/wr: 2 blocks cover 128k x 4h
    int i = b * 256 + threadIdx.x;
    int k = i >> 2, h = i & 3;
    float sl = 0.f, sr = 0.f;
    for (int d = 0; d < 128; ++d) {
        float w = W1[k * HD + h * 128 + d];
        sl += w * al1[h * 128 + d];
        sr += w * ar1[h * 128 + d];
    }
    wl[k * 4 + h] = sl;
    wr[k * 4 + h] = sr;
}

// ---------------- el/er per node: wave-per-node ----------------
__global__ __launch_bounds__(256) void eler_k(const float* __restrict__ X,
                                              const float* __restrict__ wl, const float* __restrict__ wr,
                                              float* __restrict__ el, float* __restrict__ er) {
    int w = threadIdx.x >> 6, lane = threadIdx.x & 63;
    int n = blockIdx.x * 4 + w;
    float x1 = X[(size_t)n * FIN + lane];
    float x2 = X[(size_t)n * FIN + 64 + lane];
    float pl[4], pr[4];
#pragma unroll
    for (int h = 0; h < 4; ++h) {
        pl[h] = x1 * wl[lane * 4 + h] + x2 * wl[(lane + 64) * 4 + h];
        pr[h] = x1 * wr[lane * 4 + h] + x2 * wr[(lane + 64) * 4 + h];
    }
#pragma unroll
    for (int off = 32; off > 0; off >>= 1) {
#pragma unroll
        for (int h = 0; h < 4; ++h) {
            pl[h] += __shfl_xor(pl[h], off);
            pr[h] += __shfl_xor(pr[h], off);
        }
    }
    if (lane == 0) {
        *reinterpret_cast<float4*>(el + (size_t)n * 4) = make_float4(pl[0], pl[1], pl[2], pl[3]);
        *reinterpret_cast<float4*>(er + (size_t)n * 4) = make_float4(pr[0], pr[1], pr[2], pr[3]);
    }
}

// ---------------- CSR build ----------------
__global__ void hist_k(const int* __restrict__ dst, int* __restrict__ deg) {
    int e = blockIdx.x * 256 + threadIdx.x;
    if (e < N_EDGES) atomicAdd(&deg[dst[e]], 1);
}

__global__ __launch_bounds__(1024) void scan_k(const int* __restrict__ deg,
                                               int* __restrict__ rowptr, int* __restrict__ cursor) {
    __shared__ int s[1024];
    const int ITEMS = (N_NODES + 1023) / 1024;   // 49
    int t = threadIdx.x;
    int base = t * ITEMS;
    int sum = 0;
    for (int i = 0; i < ITEMS; ++i) {
        int idx = base + i;
        if (idx < N_NODES) sum += deg[idx];
    }
    s[t] = sum;
    __syncthreads();
    for (int off = 1; off < 1024; off <<= 1) {
        int v = (t >= off) ? s[t - off] : 0;
        __syncthreads();
        s[t] += v;
        __syncthreads();
    }
    int run = s[t] - sum;   // exclusive prefix
    for (int i = 0; i < ITEMS; ++i) {
        int idx = base + i;
        if (idx < N_NODES) {
            rowptr[idx] = run;
            cursor[idx] = run;
            run += deg[idx];
        }
    }
    if (t == 1023) rowptr[N_NODES] = s[1023];
}

__global__ void fill_k(const int* __restrict__ src, const int* __restrict__ dst,
                       int* __restrict__ cursor, int* __restrict__ csr) {
    int e = blockIdx.x * 256 + threadIdx.x;
    if (e < N_EDGES) {
        int pos = atomicAdd(&cursor[dst[e]], 1);
        csr[pos] = src[e];
    }
}

// ---------------- MFMA GEMM: Z = X@W1 (y=0), RES = X@Wres1 + b1 (y=1) ----------------
__global__ __launch_bounds__(256) void gemm_k(const float* __restrict__ X,
                                              const bf16* __restrict__ W1T, const bf16* __restrict__ WresT,
                                              const float* __restrict__ bias1,
                                              bf16* __restrict__ Z, bf16* __restrict__ RES) {
    const bf16* BT = blockIdx.y ? WresT : W1T;
    bf16* outp = blockIdx.y ? RES : Z;
    const bool useBias = (blockIdx.y != 0);
    const int w = threadIdx.x >> 6;
    const int lane = threadIdx.x & 63;
    const int cl = lane & 15;        // A row within tile / D col / store row
    const int rg = lane >> 4;        // 0..3
    const int khi = rg * 8;
    const int cg = rg * 4;
    const int m0 = blockIdx.x * 64 + w * 16;
    const int row = m0 + cl;
    const int rowc = row < N_NODES ? row : N_NODES - 1;

    // A fragments: convert f32 X -> bf16 inline (k = 32*ks + khi + i)
    const float* xb = X + (size_t)rowc * FIN + khi;
    bf16x8 a[4];
#pragma unroll
    for (int ks = 0; ks < 4; ++ks) {
        f32x4 u = *reinterpret_cast<const f32x4*>(xb + 32 * ks);
        f32x4 v = *reinterpret_cast<const f32x4*>(xb + 32 * ks + 4);
        bf16x8 t = {(__bf16)u[0], (__bf16)u[1], (__bf16)u[2], (__bf16)u[3],
                    (__bf16)v[0], (__bf16)v[1], (__bf16)v[2], (__bf16)v[3]};
        a[ks] = t;
    }

    __shared__ float sbuf[4][16][17];

    for (int t = 0; t < 32; ++t) {
        const int c0 = t * 16;
        const bf16x8* bp = reinterpret_cast<const bf16x8*>(BT + (size_t)(c0 + cl) * FIN + khi);
        bf16x8 b0 = bp[0], b1 = bp[4], b2 = bp[8], b3 = bp[12];
        float bv = useBias ? bias1[c0 + cl] : 0.0f;
        f32x4 acc = {bv, bv, bv, bv};
        acc = __builtin_amdgcn_mfma_f32_16x16x32_bf16(a[0], b0, acc, 0, 0, 0);
        acc = __builtin_amdgcn_mfma_f32_16x16x32_bf16(a[1], b1, acc, 0, 0, 0);
        acc = __builtin_amdgcn_mfma_f32_16x16x32_bf16(a[2], b2, acc, 0, 0, 0);
        acc = __builtin_amdgcn_mfma_f32_16x16x32_bf16(a[3], b3, acc, 0, 0, 0);
        // D frag: col = lane&15, row = (lane>>4)*4 + i  -> transpose via per-wave LDS
#pragma unroll
        for (int i = 0; i < 4; ++i) sbuf[w][rg * 4 + i][cl] = acc[i];
        asm volatile("s_waitcnt lgkmcnt(0)" ::: "memory");
        if (row < N_NODES) {
            bf16x4 sv = {(__bf16)sbuf[w][cl][cg + 0], (__bf16)sbuf[w][cl][cg + 1],
                         (__bf16)sbuf[w][cl][cg + 2], (__bf16)sbuf[w][cl][cg + 3]};
            *reinterpret_cast<bf16x4*>(outp + (size_t)row * HD + c0 + cg) = sv;
        }
        asm volatile("s_waitcnt lgkmcnt(0)" ::: "memory");
    }
}

// ---------------- layer-1 aggregation + BN + ELU + layer-2 projections ----------------
// wave-per-node; node2[n] = {z2.xyz, el2, res2.xyz, er2}
__global__ __launch_bounds__(256) void agg1_k(
    const int* __restrict__ rowptr, const int* __restrict__ csr,
    const float* __restrict__ el, const float* __restrict__ er,
    const bf16* __restrict__ Z, const bf16* __restrict__ RES,
    const float* __restrict__ bng, const float* __restrict__ bnb,
    const float* __restrict__ bnm, const float* __restrict__ bnv,
    const float* __restrict__ W2, const float* __restrict__ Wres2,
    const float* __restrict__ al2, const float* __restrict__ ar2,
    float* __restrict__ node2) {
    __shared__ int   ssrc[4][64];
    __shared__ float spe[4][64][4];

    const int w = threadIdx.x >> 6, lane = threadIdx.x & 63;
    const int n = blockIdx.x * 4 + w;
    const int beg = rowptr[n];
    const int deg = rowptr[n + 1] - beg;
    const float4 ern = *reinterpret_cast<const float4*>(er + (size_t)n * 4);
    const int head = lane >> 4;
    const int d0 = lane * 8;

    float acc[8];
#pragma unroll
    for (int i = 0; i < 8; ++i) acc[i] = 0.f;
    float4 den = make_float4(0.f, 0.f, 0.f, 0.f);

    for (int base = 0; base < deg; base += 64) {
        const int cnt = min(64, deg - base);
        if (lane < cnt) {
            int s = csr[beg + base + lane];
            ssrc[w][lane] = s;
            float4 e4 = *reinterpret_cast<const float4*>(el + (size_t)s * 4);
            float4 p;
            float e;
            e = e4.x + ern.x; e = e > 0.f ? e : SLOPE * e; p.x = __expf(e);
            e = e4.y + ern.y; e = e > 0.f ? e : SLOPE * e; p.y = __expf(e);
            e = e4.z + ern.z; e = e > 0.f ? e : SLOPE * e; p.z = __expf(e);
            e = e4.w + ern.w; e = e > 0.f ? e : SLOPE * e; p.w = __expf(e);
            den.x += p.x; den.y += p.y; den.z += p.z; den.w += p.w;
            *reinterpret_cast<float4*>(&spe[w][lane][0]) = p;
        }
        asm volatile("s_waitcnt lgkmcnt(0)" ::: "memory");
        // gather: 2-deep software pipeline
        int s_n = ssrc[w][0];
        float p_n = spe[w][0][head];
        bf16x8 zv_n = *reinterpret_cast<const bf16x8*>(Z + (size_t)s_n * HD + d0);
        for (int jj = 0; jj < cnt; ++jj) {
            bf16x8 zv = zv_n;
            float p = p_n;
            if (jj + 1 < cnt) {
                int s2 = ssrc[w][jj + 1];
                p_n = spe[w][jj + 1][head];
                zv_n = *reinterpret_cast<const bf16x8*>(Z + (size_t)s2 * HD + d0);
            }
#pragma unroll
            for (int i = 0; i < 8; ++i) acc[i] += p * (float)zv[i];
        }
        asm volatile("s_waitcnt lgkmcnt(0)" ::: "memory");   // WAR guard before next chunk
    }

    // reduce den across wave
#pragma unroll
    for (int off = 32; off > 0; off >>= 1) {
        den.x += __shfl_xor(den.x, off);
        den.y += __shfl_xor(den.y, off);
        den.z += __shfl_xor(den.z, off);
        den.w += __shfl_xor(den.w, off);
    }
    float invh = 0.f;
    if (deg > 0) {
        float i0 = 1.f / den.x, i1 = 1.f / den.y, i2 = 1.f / den.z, i3 = 1.f / den.w;
        invh = (head & 2) ? ((head & 1) ? i3 : i2) : ((head & 1) ? i1 : i0);
    }

    // epilogue: + residual(+b1 folded), BN, ELU
    bf16x8 rv = *reinterpret_cast<const bf16x8*>(RES + (size_t)n * HD + d0);
    float o[8];
    float4 m0v = *reinterpret_cast<const float4*>(bnm + d0);
    float4 m1v = *reinterpret_cast<const float4*>(bnm + d0 + 4);
    float4 v0v = *reinterpret_cast<const float4*>(bnv + d0);
    float4 v1v = *reinterpret_cast<const float4*>(bnv + d0 + 4);
    float4 g0v = *reinterpret_cast<const float4*>(bng + d0);
    float4 g1v = *reinterpret_cast<const float4*>(bng + d0 + 4);
    float4 b0v = *reinterpret_cast<const float4*>(bnb + d0);
    float4 b1v = *reinterpret_cast<const float4*>(bnb + d0 + 4);
    float bm[8] = {m0v.x, m0v.y, m0v.z, m0v.w, m1v.x, m1v.y, m1v.z, m1v.w};
    float bvv[8] = {v0v.x, v0v.y, v0v.z, v0v.w, v1v.x, v1v.y, v1v.z, v1v.w};
    float bg[8] = {g0v.x, g0v.y, g0v.z, g0v.w, g1v.x, g1v.y, g1v.z, g1v.w};
    float bb[8] = {b0v.x, b0v.y, b0v.z, b0v.w, b1v.x, b1v.y, b1v.z, b1v.w};
#pragma unroll
    for (int i = 0; i < 8; ++i) {
        float t = acc[i] * invh + (float)rv[i];
        t = (t - bm[i]) * rsqrtf(bvv[i] + 1e-5f) * bg[i] + bb[i];
        o[i] = t > 0.f ? t : (__expf(t) - 1.f);
    }

    // layer-2 projections
    float w2v[24], wrv[24];
    const f32x4* w2p = reinterpret_cast<const f32x4*>(W2 + (size_t)d0 * 3);
    const f32x4* wrp = reinterpret_cast<const f32x4*>(Wres2 + (size_t)d0 * 3);
#pragma unroll
    for (int j = 0; j < 6; ++j) {
        f32x4 a4 = w2p[j], c4 = wrp[j];
        w2v[4 * j] = a4[0]; w2v[4 * j + 1] = a4[1]; w2v[4 * j + 2] = a4[2]; w2v[4 * j + 3] = a4[3];
        wrv[4 * j] = c4[0]; wrv[4 * j + 1] = c4[1]; wrv[4 * j + 2] = c4[2]; wrv[4 * j + 3] = c4[3];
    }
    float pz[3] = {0.f, 0.f, 0.f}, pr[3] = {0.f, 0.f, 0.f};
#pragma unroll
    for (int idx = 0; idx < 24; ++idx) {
        pz[idx % 3] += o[idx / 3] * w2v[idx];
        pr[idx % 3] += o[idx / 3] * wrv[idx];
    }
#pragma unroll
    for (int off = 32; off > 0; off >>= 1) {
        pz[0] += __shfl_xor(pz[0], off); pz[1] += __shfl_xor(pz[1], off); pz[2] += __shfl_xor(pz[2], off);
        pr[0] += __shfl_xor(pr[0], off); pr[1] += __shfl_xor(pr[1], off); pr[2] += __shfl_xor(pr[2], off);
    }
    if (lane == 0) {
        float e2l = pz[0] * al2[0] + pz[1] * al2[1] + pz[2] * al2[2];
        float e2r = pz[0] * ar2[0] + pz[1] * ar2[1] + pz[2] * ar2[2];
        float4 v0 = make_float4(pz[0], pz[1], pz[2], e2l);
        float4 v1 = make_float4(pr[0], pr[1], pr[2], e2r);
        *reinterpret_cast<float4*>(node2 + (size_t)n * 8) = v0;
        *reinterpret_cast<float4*>(node2 + (size_t)n * 8 + 4) = v1;
    }
}

// ---------------- layer-2 aggregation: wave-per-node ----------------
__global__ __launch_bounds__(256) void agg2_k(const int* __restrict__ rowptr, const int* __restrict__ csr,
                                              const float* __restrict__ node2,
                                              const float* __restrict__ b2, float* __restrict__ out) {
    int wv = threadIdx.x >> 6, lane = threadIdx.x & 63;
    int n = blockIdx.x * 4 + wv;
    int beg = rowptr[n], deg = rowptr[n + 1] - beg;
    float ern = node2[(size_t)n * 8 + 7];
    float den = 0.f, a0 = 0.f, a1 = 0.f, a2 = 0.f;
    for (int j = lane; j < deg; j += 64) {
        int s = csr[beg + j];
        float4 v = *reinterpret_cast<const float4*>(node2 + (size_t)s * 8);
        float e = v.w + ern;
        e = e > 0.f ? e : SLOPE * e;
        float p = __expf(e);
        den += p;
        a0 += p * v.x; a1 += p * v.y; a2 += p * v.z;
    }
#pragma unroll
    for (int off = 32; off > 0; off >>= 1) {
        den += __shfl_xor(den, off);
        a0 += __shfl_xor(a0, off); a1 += __shfl_xor(a1, off); a2 += __shfl_xor(a2, off);
    }
    if (lane == 0) {
        float inv = deg > 0 ? 1.f / den : 0.f;
        float4 r = *reinterpret_cast<const float4*>(node2 + (size_t)n * 8 + 4);
        out[(size_t)n * 3 + 0] = a0 * inv + r.x + b2[0];
        out[(size_t)n * 3 + 1] = a1 * inv + r.y + b2[1];
        out[(size_t)n * 3 + 2] = a2 * inv + r.z + b2[2];
    }
}

extern "C" void kernel_launch(void* const* d_in, const int* in_sizes, int n_in,
                              void* d_out, int out_size, void* d_ws, size_t ws_size,
                              hipStream_t stream) {
    const float* X     = (const float*)d_in[0];
    const int*   src   = (const int*)d_in[1];
    const int*   dst   = (const int*)d_in[2];
    const float* W1    = (const float*)d_in[3];
    const float* al1   = (const float*)d_in[4];
    const float* ar1   = (const float*)d_in[5];
    const float* b1    = (const float*)d_in[6];
    const float* Wres1 = (const float*)d_in[7];
    const float* bng   = (const float*)d_in[8];
    const float* bnb   = (const float*)d_in[9];
    const float* bnm   = (const float*)d_in[10];
    const float* bnv   = (const float*)d_in[11];
    const float* W2    = (const float*)d_in[12];
    const float* al2   = (const float*)d_in[13];
    const float* ar2   = (const float*)d_in[14];
    const float* b2    = (const float*)d_in[15];
    const float* Wres2 = (const float*)d_in[16];
    float* out = (float*)d_out;

    char* p = (char*)d_ws;
    auto carve = [&](size_t bytes) -> char* {
        char* r = p;
        p += (bytes + 255) & ~(size_t)255;
        return r;
    };
    bf16*  W1T    = (bf16*)carve((size_t)HD * FIN * 2);
    bf16*  WresT  = (bf16*)carve((size_t)HD * FIN * 2);
    float* wl     = (float*)carve((size_t)FIN * 4 * 4);
    float* wr     = (float*)carve((size_t)FIN * 4 * 4);
    float* el     = (float*)carve((size_t)N_NODES * 4 * 4);
    float* er     = (float*)carve((size_t)N_NODES * 4 * 4);
    int*   deg    = (int*)carve((size_t)N_NODES * 4);
    int*   rowptr = (int*)carve((size_t)(N_NODES + 1) * 4);
    int*   cursor = (int*)carve((size_t)N_NODES * 4);
    int*   csr    = (int*)carve((size_t)N_EDGES * 4);
    bf16*  Z      = (bf16*)carve((size_t)N_NODES * HD * 2);
    bf16*  RES    = (bf16*)carve((size_t)N_NODES * HD * 2);
    float* node2  = (float*)carve((size_t)N_NODES * 8 * 4);
    size_t need = (size_t)(p - (char*)d_ws);
    if (need > ws_size) {
        sentinel_k<<<(out_size + 255) / 256, 256, 0, stream>>>(out, out_size);
        return;
    }

    prep_k<<<196 + 512 + 2, 256, 0, stream>>>(W1, Wres1, al1, ar1, W1T, WresT, wl, wr, deg);
    eler_k<<<N_NODES / 4, 256, 0, stream>>>(X, wl, wr, el, er);
    hist_k<<<(N_EDGES + 255) / 256, 256, 0, stream>>>(dst, deg);
    scan_k<<<1, 1024, 0, stream>>>(deg, rowptr, cursor);
    fill_k<<<(N_EDGES + 255) / 256, 256, 0, stream>>>(src, dst, cursor, csr);
    gemm_k<<<dim3((N_NODES + 63) / 64, 2), 256, 0, stream>>>(X, W1T, WresT, b1, Z, RES);
    agg1_k<<<N_NODES / 4, 256, 0, stream>>>(rowptr, csr, el, er, Z, RES,
                                            bng, bnb, bnm, bnv, W2, Wres2, al2, ar2, node2);
    agg2_k<<<N_NODES / 4, 256, 0, stream>>>(rowptr, csr, node2, b2, out);
}

// Round 4
// 303.087 us; speedup vs baseline: 1.7272x; 1.3773x over previous
//
#include <hip/hip_runtime.h>
#include <hip/hip_bf16.h>

#define N_NODES 50000
#define N_EDGES 400000
#define FIN     128
#define HD      512
#define SLOPE   0.2f

typedef __hip_bfloat16 bf16;
typedef __bf16 bf16x8 __attribute__((ext_vector_type(8)));
typedef __bf16 bf16x4 __attribute__((ext_vector_type(4)));
typedef float  f32x4  __attribute__((ext_vector_type(4)));

// ---------------- sentinel (workspace too small diagnostic) ----------------
__global__ void sentinel_k(float* out, int n) {
    int i = blockIdx.x * 256 + threadIdx.x;
    if (i < n) out[i] = 12288.0f;
}

// ---------------- prep: zero deg | transpose W1/Wres1 -> bf16 | wl/wr ----------------
__global__ __launch_bounds__(256) void prep_k(const float* __restrict__ W1, const float* __restrict__ Wres1,
                                              const float* __restrict__ al1, const float* __restrict__ ar1,
                                              bf16* __restrict__ W1T, bf16* __restrict__ WresT,
                                              float* __restrict__ wl, float* __restrict__ wr,
                                              int* __restrict__ deg) {
    int b = blockIdx.x;
    if (b < 196) {                       // zero deg
        int i = b * 256 + threadIdx.x;
        if (i < N_NODES) deg[i] = 0;
        return;
    }
    b -= 196;
    if (b < 512) {                       // transpose both weight matrices, 2 col-units/block
        int cu = b * 2 + (threadIdx.x >> 7);
        int k = threadIdx.x & 127;
        if (cu < 512) W1T[cu * FIN + k] = __float2bfloat16(W1[k * HD + cu]);
        else          WresT[(cu - 512) * FIN + k] = __float2bfloat16(Wres1[k * HD + (cu - 512)]);
        return;
    }
    b -= 512;                            // wl/wr: 2 blocks cover 128k x 4h
    int i = b * 256 + threadIdx.x;
    int k = i >> 2, h = i & 3;
    float sl = 0.f, sr = 0.f;
    for (int d = 0; d < 128; ++d) {
        float w = W1[k * HD + h * 128 + d];
        sl += w * al1[h * 128 + d];
        sr += w * ar1[h * 128 + d];
    }
    wl[k * 4 + h] = sl;
    wr[k * 4 + h] = sr;
}

// ---------------- el/er per node: wave-per-node ----------------
__global__ __launch_bounds__(256) void eler_k(const float* __restrict__ X,
                                              const float* __restrict__ wl, const float* __restrict__ wr,
                                              float* __restrict__ el, float* __restrict__ er) {
    int w = threadIdx.x >> 6, lane = threadIdx.x & 63;
    int n = blockIdx.x * 4 + w;
    float x1 = X[(size_t)n * FIN + lane];
    float x2 = X[(size_t)n * FIN + 64 + lane];
    float pl[4], pr[4];
#pragma unroll
    for (int h = 0; h < 4; ++h) {
        pl[h] = x1 * wl[lane * 4 + h] + x2 * wl[(lane + 64) * 4 + h];
        pr[h] = x1 * wr[lane * 4 + h] + x2 * wr[(lane + 64) * 4 + h];
    }
#pragma unroll
    for (int off = 32; off > 0; off >>= 1) {
#pragma unroll
        for (int h = 0; h < 4; ++h) {
            pl[h] += __shfl_xor(pl[h], off);
            pr[h] += __shfl_xor(pr[h], off);
        }
    }
    if (lane == 0) {
        *reinterpret_cast<float4*>(el + (size_t)n * 4) = make_float4(pl[0], pl[1], pl[2], pl[3]);
        *reinterpret_cast<float4*>(er + (size_t)n * 4) = make_float4(pr[0], pr[1], pr[2], pr[3]);
    }
}

// ---------------- CSR build ----------------
__global__ void hist_k(const int* __restrict__ dst, int* __restrict__ deg) {
    int e = blockIdx.x * 256 + threadIdx.x;
    if (e < N_EDGES) atomicAdd(&deg[dst[e]], 1);
}

// 3-phase parallel exclusive scan of deg[50000] -> rowptr/cursor
__global__ __launch_bounds__(256) void scan1_k(const int* __restrict__ deg,
                                               int* __restrict__ rowptr, int* __restrict__ blksum) {
    __shared__ int wsum[4];
    int t = threadIdx.x, b = blockIdx.x;
    int i = b * 256 + t;
    int v = (i < N_NODES) ? deg[i] : 0;
    int lane = t & 63, w = t >> 6;
    int x = v;
#pragma unroll
    for (int off = 1; off < 64; off <<= 1) {
        int y = __shfl_up(x, off);
        if (lane >= off) x += y;
    }
    if (lane == 63) wsum[w] = x;
    __syncthreads();
    int wadd = 0;
    if (w > 0) wadd += wsum[0];
    if (w > 1) wadd += wsum[1];
    if (w > 2) wadd += wsum[2];
    int incl = x + wadd;
    if (i < N_NODES) rowptr[i] = incl - v;     // block-local exclusive
    if (t == 255) blksum[b] = incl;            // block total
}

__global__ __launch_bounds__(256) void scan2_k(int* __restrict__ blksum) {
    __shared__ int wsum[4];
    int t = threadIdx.x;
    int v = (t < 196) ? blksum[t] : 0;
    int lane = t & 63, w = t >> 6;
    int x = v;
#pragma unroll
    for (int off = 1; off < 64; off <<= 1) {
        int y = __shfl_up(x, off);
        if (lane >= off) x += y;
    }
    if (lane == 63) wsum[w] = x;
    __syncthreads();
    int wadd = 0;
    if (w > 0) wadd += wsum[0];
    if (w > 1) wadd += wsum[1];
    if (w > 2) wadd += wsum[2];
    if (t < 196) blksum[t] = x + wadd - v;     // exclusive block offsets
}

__global__ __launch_bounds__(256) void scan3_k(const int* __restrict__ blksum,
                                               int* __restrict__ rowptr, int* __restrict__ cursor) {
    int b = blockIdx.x;
    int i = b * 256 + threadIdx.x;
    if (i < N_NODES) {
        int v = rowptr[i] + blksum[b];
        rowptr[i] = v;
        cursor[i] = v;
    }
    if (i == 0) rowptr[N_NODES] = N_EDGES;
}

__global__ void fill_k(const int* __restrict__ src, const int* __restrict__ dst,
                       int* __restrict__ cursor, int* __restrict__ csr) {
    int e = blockIdx.x * 256 + threadIdx.x;
    if (e < N_EDGES) {
        int pos = atomicAdd(&cursor[dst[e]], 1);
        csr[pos] = src[e];
    }
}

// ---------------- MFMA GEMM: Z = X@W1 (y=0), RES = X@Wres1 + b1 (y=1) ----------------
__global__ __launch_bounds__(256) void gemm_k(const float* __restrict__ X,
                                              const bf16* __restrict__ W1T, const bf16* __restrict__ WresT,
                                              const float* __restrict__ bias1,
                                              bf16* __restrict__ Z, bf16* __restrict__ RES) {
    const bf16* BT = blockIdx.y ? WresT : W1T;
    bf16* outp = blockIdx.y ? RES : Z;
    const bool useBias = (blockIdx.y != 0);
    const int w = threadIdx.x >> 6;
    const int lane = threadIdx.x & 63;
    const int cl = lane & 15;        // A row within tile / D col / store row
    const int rg = lane >> 4;        // 0..3
    const int khi = rg * 8;
    const int cg = rg * 4;
    const int m0 = blockIdx.x * 64 + w * 16;
    const int row = m0 + cl;
    const int rowc = row < N_NODES ? row : N_NODES - 1;

    // A fragments: convert f32 X -> bf16 inline (k = 32*ks + khi + i)
    const float* xb = X + (size_t)rowc * FIN + khi;
    bf16x8 a[4];
#pragma unroll
    for (int ks = 0; ks < 4; ++ks) {
        f32x4 u = *reinterpret_cast<const f32x4*>(xb + 32 * ks);
        f32x4 v = *reinterpret_cast<const f32x4*>(xb + 32 * ks + 4);
        bf16x8 t = {(__bf16)u[0], (__bf16)u[1], (__bf16)u[2], (__bf16)u[3],
                    (__bf16)v[0], (__bf16)v[1], (__bf16)v[2], (__bf16)v[3]};
        a[ks] = t;
    }

    __shared__ float sbuf[4][16][17];

    for (int t = 0; t < 32; ++t) {
        const int c0 = t * 16;
        const bf16x8* bp = reinterpret_cast<const bf16x8*>(BT + (size_t)(c0 + cl) * FIN + khi);
        bf16x8 b0 = bp[0], b1 = bp[4], b2 = bp[8], b3 = bp[12];
        float bv = useBias ? bias1[c0 + cl] : 0.0f;
        f32x4 acc = {bv, bv, bv, bv};
        acc = __builtin_amdgcn_mfma_f32_16x16x32_bf16(a[0], b0, acc, 0, 0, 0);
        acc = __builtin_amdgcn_mfma_f32_16x16x32_bf16(a[1], b1, acc, 0, 0, 0);
        acc = __builtin_amdgcn_mfma_f32_16x16x32_bf16(a[2], b2, acc, 0, 0, 0);
        acc = __builtin_amdgcn_mfma_f32_16x16x32_bf16(a[3], b3, acc, 0, 0, 0);
        // D frag: col = lane&15, row = (lane>>4)*4 + i  -> transpose via per-wave LDS
#pragma unroll
        for (int i = 0; i < 4; ++i) sbuf[w][rg * 4 + i][cl] = acc[i];
        asm volatile("s_waitcnt lgkmcnt(0)" ::: "memory");
        if (row < N_NODES) {
            bf16x4 sv = {(__bf16)sbuf[w][cl][cg + 0], (__bf16)sbuf[w][cl][cg + 1],
                         (__bf16)sbuf[w][cl][cg + 2], (__bf16)sbuf[w][cl][cg + 3]};
            *reinterpret_cast<bf16x4*>(outp + (size_t)row * HD + c0 + cg) = sv;
        }
        asm volatile("s_waitcnt lgkmcnt(0)" ::: "memory");
    }
}

// ---------------- layer-1 aggregation + BN + ELU + layer-2 projections ----------------
// wave-per-node; node2[n] = {z2.xyz, el2, res2.xyz, er2}
__global__ __launch_bounds__(256) void agg1_k(
    const int* __restrict__ rowptr, const int* __restrict__ csr,
    const float* __restrict__ el, const float* __restrict__ er,
    const bf16* __restrict__ Z, const bf16* __restrict__ RES,
    const float* __restrict__ bng, const float* __restrict__ bnb,
    const float* __restrict__ bnm, const float* __restrict__ bnv,
    const float* __restrict__ W2, const float* __restrict__ Wres2,
    const float* __restrict__ al2, const float* __restrict__ ar2,
    float* __restrict__ node2) {
    __shared__ int   ssrc[4][64];
    __shared__ float spe[4][64][4];

    const int w = threadIdx.x >> 6, lane = threadIdx.x & 63;
    const int n = blockIdx.x * 4 + w;
    const int beg = rowptr[n];
    const int deg = rowptr[n + 1] - beg;
    const float4 ern = *reinterpret_cast<const float4*>(er + (size_t)n * 4);
    const int head = lane >> 4;
    const int d0 = lane * 8;

    float acc[8];
#pragma unroll
    for (int i = 0; i < 8; ++i) acc[i] = 0.f;
    float4 den = make_float4(0.f, 0.f, 0.f, 0.f);

    for (int base = 0; base < deg; base += 64) {
        const int cnt = min(64, deg - base);
        if (lane < cnt) {
            int s = csr[beg + base + lane];
            ssrc[w][lane] = s;
            float4 e4 = *reinterpret_cast<const float4*>(el + (size_t)s * 4);
            float4 p;
            float e;
            e = e4.x + ern.x; e = e > 0.f ? e : SLOPE * e; p.x = __expf(e);
            e = e4.y + ern.y; e = e > 0.f ? e : SLOPE * e; p.y = __expf(e);
        e = e4.z + ern.z; e = e > 0.f ? e : SLOPE * e; p.z = __expf(e);
            e = e4.w + ern.w; e = e > 0.f ? e : SLOPE * e; p.w = __expf(e);
            den.x += p.x; den.y += p.y; den.z += p.z; den.w += p.w;
            *reinterpret_cast<float4*>(&spe[w][lane][0]) = p;
        }
        asm volatile("s_waitcnt lgkmcnt(0)" ::: "memory");
        // gather: 2-deep software pipeline
        int s_n = ssrc[w][0];
        float p_n = spe[w][0][head];
        bf16x8 zv_n = *reinterpret_cast<const bf16x8*>(Z + (size_t)s_n * HD + d0);
        for (int jj = 0; jj < cnt; ++jj) {
            bf16x8 zv = zv_n;
            float p = p_n;
            if (jj + 1 < cnt) {
                int s2 = ssrc[w][jj + 1];
                p_n = spe[w][jj + 1][head];
                zv_n = *reinterpret_cast<const bf16x8*>(Z + (size_t)s2 * HD + d0);
            }
#pragma unroll
            for (int i = 0; i < 8; ++i) acc[i] += p * (float)zv[i];
        }
        asm volatile("s_waitcnt lgkmcnt(0)" ::: "memory");   // WAR guard before next chunk
    }

    // reduce den across wave
#pragma unroll
    for (int off = 32; off > 0; off >>= 1) {
        den.x += __shfl_xor(den.x, off);
        den.y += __shfl_xor(den.y, off);
        den.z += __shfl_xor(den.z, off);
        den.w += __shfl_xor(den.w, off);
    }
    float invh = 0.f;
    if (deg > 0) {
        float i0 = 1.f / den.x, i1 = 1.f / den.y, i2 = 1.f / den.z, i3 = 1.f / den.w;
        invh = (head & 2) ? ((head & 1) ? i3 : i2) : ((head & 1) ? i1 : i0);
    }

    // epilogue: + residual(+b1 folded), BN, ELU
    bf16x8 rv = *reinterpret_cast<const bf16x8*>(RES + (size_t)n * HD + d0);
    float o[8];
    float4 m0v = *reinterpret_cast<const float4*>(bnm + d0);
    float4 m1v = *reinterpret_cast<const float4*>(bnm + d0 + 4);
    float4 v0v = *reinterpret_cast<const float4*>(bnv + d0);
    float4 v1v = *reinterpret_cast<const float4*>(bnv + d0 + 4);
    float4 g0v = *reinterpret_cast<const float4*>(bng + d0);
    float4 g1v = *reinterpret_cast<const float4*>(bng + d0 + 4);
    float4 b0v = *reinterpret_cast<const float4*>(bnb + d0);
    float4 b1v = *reinterpret_cast<const float4*>(bnb + d0 + 4);
    float bm[8] = {m0v.x, m0v.y, m0v.z, m0v.w, m1v.x, m1v.y, m1v.z, m1v.w};
    float bvv[8] = {v0v.x, v0v.y, v0v.z, v0v.w, v1v.x, v1v.y, v1v.z, v1v.w};
    float bg[8] = {g0v.x, g0v.y, g0v.z, g0v.w, g1v.x, g1v.y, g1v.z, g1v.w};
    float bb[8] = {b0v.x, b0v.y, b0v.z, b0v.w, b1v.x, b1v.y, b1v.z, b1v.w};
#pragma unroll
    for (int i = 0; i < 8; ++i) {
        float t = acc[i] * invh + (float)rv[i];
        t = (t - bm[i]) * rsqrtf(bvv[i] + 1e-5f) * bg[i] + bb[i];
        o[i] = t > 0.f ? t : (__expf(t) - 1.f);
    }

    // layer-2 projections
    float w2v[24], wrv[24];
    const f32x4* w2p = reinterpret_cast<const f32x4*>(W2 + (size_t)d0 * 3);
    const f32x4* wrp = reinterpret_cast<const f32x4*>(Wres2 + (size_t)d0 * 3);
#pragma unroll
    for (int j = 0; j < 6; ++j) {
        f32x4 a4 = w2p[j], c4 = wrp[j];
        w2v[4 * j] = a4[0]; w2v[4 * j + 1] = a4[1]; w2v[4 * j + 2] = a4[2]; w2v[4 * j + 3] = a4[3];
        wrv[4 * j] = c4[0]; wrv[4 * j + 1] = c4[1]; wrv[4 * j + 2] = c4[2]; wrv[4 * j + 3] = c4[3];
    }
    float pz[3] = {0.f, 0.f, 0.f}, pr[3] = {0.f, 0.f, 0.f};
#pragma unroll
    for (int idx = 0; idx < 24; ++idx) {
        pz[idx % 3] += o[idx / 3] * w2v[idx];
        pr[idx % 3] += o[idx / 3] * wrv[idx];
    }
#pragma unroll
    for (int off = 32; off > 0; off >>= 1) {
        pz[0] += __shfl_xor(pz[0], off); pz[1] += __shfl_xor(pz[1], off); pz[2] += __shfl_xor(pz[2], off);
        pr[0] += __shfl_xor(pr[0], off); pr[1] += __shfl_xor(pr[1], off); pr[2] += __shfl_xor(pr[2], off);
    }
    if (lane == 0) {
        float e2l = pz[0] * al2[0] + pz[1] * al2[1] + pz[2] * al2[2];
        float e2r = pz[0] * ar2[0] + pz[1] * ar2[1] + pz[2] * ar2[2];
        float4 v0 = make_float4(pz[0], pz[1], pz[2], e2l);
        float4 v1 = make_float4(pr[0], pr[1], pr[2], e2r);
        *reinterpret_cast<float4*>(node2 + (size_t)n * 8) = v0;
        *reinterpret_cast<float4*>(node2 + (size_t)n * 8 + 4) = v1;
    }
}

// ---------------- layer-2 aggregation: wave-per-node ----------------
__global__ __launch_bounds__(256) void agg2_k(const int* __restrict__ rowptr, const int* __restrict__ csr,
                                              const float* __restrict__ node2,
                                              const float* __restrict__ b2, float* __restrict__ out) {
    int wv = threadIdx.x >> 6, lane = threadIdx.x & 63;
    int n = blockIdx.x * 4 + wv;
    int beg = rowptr[n], deg = rowptr[n + 1] - beg;
    float ern = node2[(size_t)n * 8 + 7];
    float den = 0.f, a0 = 0.f, a1 = 0.f, a2 = 0.f;
    for (int j = lane; j < deg; j += 64) {
        int s = csr[beg + j];
        float4 v = *reinterpret_cast<const float4*>(node2 + (size_t)s * 8);
        float e = v.w + ern;
        e = e > 0.f ? e : SLOPE * e;
        float p = __expf(e);
        den += p;
        a0 += p * v.x; a1 += p * v.y; a2 += p * v.z;
    }
#pragma unroll
    for (int off = 32; off > 0; off >>= 1) {
        den += __shfl_xor(den, off);
        a0 += __shfl_xor(a0, off); a1 += __shfl_xor(a1, off); a2 += __shfl_xor(a2, off);
    }
    if (lane == 0) {
        float inv = deg > 0 ? 1.f / den : 0.f;
        float4 r = *reinterpret_cast<const float4*>(node2 + (size_t)n * 8 + 4);
        out[(size_t)n * 3 + 0] = a0 * inv + r.x + b2[0];
        out[(size_t)n * 3 + 1] = a1 * inv + r.y + b2[1];
        out[(size_t)n * 3 + 2] = a2 * inv + r.z + b2[2];
    }
}

extern "C" void kernel_launch(void* const* d_in, const int* in_sizes, int n_in,
                              void* d_out, int out_size, void* d_ws, size_t ws_size,
                              hipStream_t stream) {
    const float* X     = (const float*)d_in[0];
    const int*   src   = (const int*)d_in[1];
    const int*   dst   = (const int*)d_in[2];
    const float* W1    = (const float*)d_in[3];
    const float* al1   = (const float*)d_in[4];
    const float* ar1   = (const float*)d_in[5];
    const float* b1    = (const float*)d_in[6];
    const float* Wres1 = (const float*)d_in[7];
    const float* bng   = (const float*)d_in[8];
    const float* bnb   = (const float*)d_in[9];
    const float* bnm   = (const float*)d_in[10];
    const float* bnv   = (const float*)d_in[11];
    const float* W2    = (const float*)d_in[12];
    const float* al2   = (const float*)d_in[13];
    const float* ar2   = (const float*)d_in[14];
    const float* b2    = (const float*)d_in[15];
    const float* Wres2 = (const float*)d_in[16];
    float* out = (float*)d_out;

    char* p = (char*)d_ws;
    auto carve = [&](size_t bytes) -> char* {
        char* r = p;
        p += (bytes + 255) & ~(size_t)255;
        return r;
    };
    bf16*  W1T    = (bf16*)carve((size_t)HD * FIN * 2);
    bf16*  WresT  = (bf16*)carve((size_t)HD * FIN * 2);
    float* wl     = (float*)carve((size_t)FIN * 4 * 4);
    float* wr     = (float*)carve((size_t)FIN * 4 * 4);
    float* el     = (float*)carve((size_t)N_NODES * 4 * 4);
    float* er     = (float*)carve((size_t)N_NODES * 4 * 4);
    int*   deg    = (int*)carve((size_t)N_NODES * 4);
    int*   rowptr = (int*)carve((size_t)(N_NODES + 1) * 4);
    int*   cursor = (int*)carve((size_t)N_NODES * 4);
    int*   blksum = (int*)carve((size_t)256 * 4);
    int*   csr    = (int*)carve((size_t)N_EDGES * 4);
    bf16*  Z      = (bf16*)carve((size_t)N_NODES * HD * 2);
    bf16*  RES    = (bf16*)carve((size_t)N_NODES * HD * 2);
    float* node2  = (float*)carve((size_t)N_NODES * 8 * 4);
    size_t need = (size_t)(p - (char*)d_ws);
    if (need > ws_size) {
        sentinel_k<<<(out_size + 255) / 256, 256, 0, stream>>>(out, out_size);
        return;
    }

    prep_k<<<196 + 512 + 2, 256, 0, stream>>>(W1, Wres1, al1, ar1, W1T, WresT, wl, wr, deg);
    eler_k<<<N_NODES / 4, 256, 0, stream>>>(X, wl, wr, el, er);
    hist_k<<<(N_EDGES + 255) / 256, 256, 0, stream>>>(dst, deg);
    scan1_k<<<196, 256, 0, stream>>>(deg, rowptr, blksum);
    scan2_k<<<1, 256, 0, stream>>>(blksum);
    scan3_k<<<196, 256, 0, stream>>>(blksum, rowptr, cursor);
    fill_k<<<(N_EDGES + 255) / 256, 256, 0, stream>>>(src, dst, cursor, csr);
    gemm_k<<<dim3((N_NODES + 63) / 64, 2), 256, 0, stream>>>(X, W1T, WresT, b1, Z, RES);
    agg1_k<<<N_NODES / 4, 256, 0, stream>>>(rowptr, csr, el, er, Z, RES,
                                            bng, bnb, bnm, bnv, W2, Wres2, al2, ar2, node2);
    agg2_k<<<N_NODES / 4, 256, 0, stream>>>(rowptr, csr, node2, b2, out);
}